// Round 2
// baseline (134.236 us; speedup 1.0000x reference)
//
#include <hip/hip_runtime.h>
#include <hip/hip_bf16.h>

// Problem constants
#define NQ 8192            // B*S flattened tokens
#define DIM 64             // embed dim
#define SPLITS 16          // key-dimension split (partials merged by kernel 3)
#define QBLK 64            // queries per block = ONE wave (no intra-block sync)
#define BN 64              // keys per tile
#define KEYS_PER_SPLIT (NQ / SPLITS)       // 512
#define NTILES (KEYS_PER_SPLIT / BN)       // 8
#define GRID_FLASH ((NQ / QBLK) * SPLITS)  // 2048
#define MERGEB 512         // merge grid (2 blocks/CU)
#define MROWS (NQ / MERGEB)                // 16 rows per merge block
#define SC2 0.51012301920911057f           // (1/sqrt(8)) * log2(e), folded into qq
#define KSTR 72            // LDS row stride in shorts (qkv/merge weight tiles)

typedef short s8v __attribute__((ext_vector_type(8)));   // 8 x bf16 bits
typedef short s4v __attribute__((ext_vector_type(4)));   // 4 x bf16 bits
typedef float f4v __attribute__((ext_vector_type(4)));
typedef int   i4v __attribute__((ext_vector_type(4)));

__device__ __forceinline__ float b2f(short s) {
  unsigned int u = ((unsigned int)(unsigned short)s) << 16;
  return __uint_as_float(u);
}
__device__ __forceinline__ short f2b(float f) {
  __hip_bfloat16 h = __float2bfloat16(f);
  return *reinterpret_cast<short*>(&h);
}
__device__ __forceinline__ int pack_bf16x2(float a, float b) {
  union { __hip_bfloat162 h; int i; } u;
  u.h = __float22bfloat162_rn(make_float2(a, b));
  return u.i;
}
__device__ __forceinline__ float fast_exp2(float x) {
#if __has_builtin(__builtin_amdgcn_exp2f)
  return __builtin_amdgcn_exp2f(x);   // single v_exp_f32, no OCML call
#else
  return exp2f(x);
#endif
}

// ---------------- QKV projection + quantum map (fp32 in, bf16 out) ----------
// MFMA version: Y[8192 x 192] = X[8192 x 64] @ [wq;wk;wv]^T via 16x16x32 bf16
// MFMA (A = W rows -> C rows = out-dim, B = X rows -> C cols = token), then
// the cos(theta)*cos(y) epilogue on C fragments.
// kvT is FRAGMENT-LINEAR TILED (8192 shorts per 64-key tile = 8 K-chunks then
// 8 V-chunks of 512 = chunk*512 + lane*8 + j) so the flash kernel reads MFMA
// fragments DIRECTLY from L2 with coalesced 16B/lane loads - no LDS staging.
#define QKV_TPB 128        // 2 waves
#define QKV_ROWS 32        // tokens per block (16 per wave)
__global__ __launch_bounds__(128) void qkv_kernel(
    const float* __restrict__ x,
    const float* __restrict__ wq, const float* __restrict__ bq,
    const float* __restrict__ wk, const float* __restrict__ bk,
    const float* __restrict__ wv, const float* __restrict__ bv,
    const float* __restrict__ theta,
    short* __restrict__ qq, short* __restrict__ kvT) {
  __shared__ __align__(16) short wsh[3 * DIM][KSTR];     // bf16 stacked weights
  __shared__ __align__(16) short xsb[QKV_ROWS][KSTR];    // bf16 x rows
  __shared__ __align__(16) float bb[3 * DIM];            // stacked biases
  __shared__ __align__(16) float ctl[DIM];               // cos(theta)
  int tid = threadIdx.x;
  // stage weights (3*64 rows x 16 float4 = 3072 iters / 128 thr = 24 each)
  for (int i = tid; i < 3 * DIM * 16; i += QKV_TPB) {
    int m = i >> 10;
    int rem = i & 1023;
    int r = rem >> 4, c4 = (rem & 15) << 2;
    const float* src = (m == 0) ? wq : (m == 1) ? wk : wv;
    float4 w = *(const float4*)&src[r * DIM + c4];
    s4v p = {f2b(w.x), f2b(w.y), f2b(w.z), f2b(w.w)};
    *(s4v*)&wsh[m * DIM + r][c4] = p;
  }
  int rowbase = blockIdx.x * QKV_ROWS;
  for (int i = tid; i < QKV_ROWS * 16; i += QKV_TPB) {
    int r = i >> 4, c4 = (i & 15) << 2;
    float4 v = *(const float4*)&x[(rowbase + r) * DIM + c4];
    s4v p = {f2b(v.x), f2b(v.y), f2b(v.z), f2b(v.w)};
    *(s4v*)&xsb[r][c4] = p;
  }
  if (tid < DIM) {
    ctl[tid] = __cosf(theta[tid]);
    bb[tid] = bq[tid];
    bb[DIM + tid] = bk[tid];
    bb[2 * DIM + tid] = bv[tid];
  }
  __syncthreads();

  int wave = tid >> 6, lane = tid & 63;
  int l15 = lane & 15, quad = lane >> 4;
  int n = rowbase + wave * 16 + l15;   // this lane's token (as C column)

  // B-frags: X[token = l15][k = quad*8 + j], two k-halves
  s8v xf0 = *(const s8v*)&xsb[wave * 16 + l15][quad * 8];
  s8v xf1 = *(const s8v*)&xsb[wave * 16 + l15][quad * 8 + 32];

  size_t tb = (size_t)(n >> 6) * 8192;
  int nperm = (n & 3) | ((n & 16) >> 2);
  size_t vbase = tb + 4096 + ((n & 32) >> 5) * 2048 + ((n & 15) >> 2) * 128 + nperm;

#pragma unroll
  for (int mt = 0; mt < 12; ++mt) {
    // A-frag: W[out-dim = mt*16 + l15][k = quad*8 + j]
    s8v wf0 = *(const s8v*)&wsh[mt * 16 + l15][quad * 8];
    s8v wf1 = *(const s8v*)&wsh[mt * 16 + l15][quad * 8 + 32];
    f4v acc = (f4v){0.f, 0.f, 0.f, 0.f};
    acc = __builtin_amdgcn_mfma_f32_16x16x32_bf16(wf0, xf0, acc, 0, 0, 0);
    acc = __builtin_amdgcn_mfma_f32_16x16x32_bf16(wf1, xf1, acc, 0, 0, 0);
    // C[row = out-dim = mt*16 + quad*4 + r][col = token = l15]
    int d0 = mt * 16 + quad * 4;
    float4 bias = *(const float4*)&bb[d0];
    float4 ct4 = *(const float4*)&ctl[d0 & 63];
    float y0 = __cosf(acc[0] + bias.x) * ct4.x;
    float y1 = __cosf(acc[1] + bias.y) * ct4.y;
    float y2 = __cosf(acc[2] + bias.z) * ct4.z;
    float y3 = __cosf(acc[3] + bias.w) * ct4.w;
    if (mt < 4) {
      s4v p = {f2b(SC2 * y0), f2b(SC2 * y1), f2b(SC2 * y2), f2b(SC2 * y3)};
      *(s4v*)&qq[(size_t)n * DIM + d0] = p;
    } else if (mt < 8) {
      int e = d0 - 64;   // e&7 advances with r; higher fields constant over r
      size_t idx = tb + ((n & 63) >> 4) * 1024 + (e >> 5) * 512 +
                   ((e & 31) >> 3) * 128 + (n & 15) * 8 + (e & 7);
      s4v p = {f2b(y0), f2b(y1), f2b(y2), f2b(y3)};
      *(s4v*)&kvT[idx] = p;
    } else {
      int e0 = d0 - 128;
      float ys[4] = {y0, y1, y2, y3};
#pragma unroll
      for (int r = 0; r < 4; ++r) {
        int e = e0 + r;
        kvT[vbase + (e >> 4) * 512 + (e & 15) * 8] = f2b(ys[r]);
      }
    }
  }
}

// ---------------- Flash attention (no-max streaming softmax) ----------------
// |s| <= 64/sqrt(8) = 22.6 -> exp(s) <= 6.6e9, row sums <= 5.5e13: fp32-safe,
// so no running max; split partials merge by pure summation.
// QK computed as S^T (A=K, B=Q): exp'd C-regs are directly a PV A-operand.
// PV uses K=32 MFMA with the key-perm baked into kvT's V chunks.
// Row sums l computed by an extra MFMA against an all-ones B fragment.
//
// NO LDS, NO BARRIERS: kvT is 2 MB (fits per-XCD L2) and fragment-linear, so
// each wave reads its K/V MFMA fragments directly from global with coalesced
// 16B/lane loads (Common-mistake #7: staging L2-fit data is pure overhead).
// One wave per block, grid 2048 -> ~3 waves/SIMD, waves free-run.
__global__ __launch_bounds__(64, 3) void flash_kernel(
    const short* __restrict__ qq, const short* __restrict__ kvT,
    short* __restrict__ pO, short* __restrict__ pL) {
  int lane = threadIdx.x & 63;
  int l15 = lane & 15, quad = lane >> 4;
  int qblock = blockIdx.x >> 4, split = blockIdx.x & 15;
  int qbase = qblock * QBLK;

  // Q B-frags: B[n=query=l15][k=dim=quad*8+j], two k-halves, 4 q-subtiles
  s8v qf[4][2];
#pragma unroll
  for (int qt = 0; qt < 4; ++qt) {
    const short* qr = qq + (qbase + qt * 16 + l15) * DIM + quad * 8;
    qf[qt][0] = *(const s8v*)qr;
    qf[qt][1] = *(const s8v*)(qr + 32);
  }

  const short ONE = (short)0x3F80;  // bf16 1.0
  const s8v ones = {ONE, ONE, ONE, ONE, ONE, ONE, ONE, ONE};

  f4v o[4][4], ol[4];
#pragma unroll
  for (int qt = 0; qt < 4; ++qt) {
    ol[qt] = (f4v){0.f, 0.f, 0.f, 0.f};
#pragma unroll
    for (int c = 0; c < 4; ++c) o[qt][c] = (f4v){0.f, 0.f, 0.f, 0.f};
  }

  // fragment-linear tile pointer for this lane (chunk c lives at c*512+lane*8)
  const short* kv0 = kvT + (size_t)(split * NTILES) * 8192 + lane * 8;

  for (int t = 0; t < NTILES; ++t) {
    const short* tb = kv0 + t * 8192;

#pragma unroll
    for (int kp = 0; kp < 2; ++kp) {   // pair of 16-key sub-tiles
      i4v pai[4];                      // exp'd P, A-operand bits, per qt
#pragma unroll
      for (int h = 0; h < 2; ++h) {
        int kt = kp * 2 + h;
        s8v kf0 = *(const s8v*)(tb + (kt * 2) * 512);
        s8v kf1 = *(const s8v*)(tb + (kt * 2 + 1) * 512);
#pragma unroll
        for (int qt = 0; qt < 4; ++qt) {
          f4v acc = (f4v){0.f, 0.f, 0.f, 0.f};
          acc = __builtin_amdgcn_mfma_f32_16x16x32_bf16(kf0, qf[qt][0], acc, 0, 0, 0);
          acc = __builtin_amdgcn_mfma_f32_16x16x32_bf16(kf1, qf[qt][1], acc, 0, 0, 0);
          // acc[r] = SC2*S^T[key=kt*16+quad*4+r][query=qt*16+l15]
          pai[qt][h * 2]     = pack_bf16x2(fast_exp2(acc[0]), fast_exp2(acc[1]));
          pai[qt][h * 2 + 1] = pack_bf16x2(fast_exp2(acc[2]), fast_exp2(acc[3]));
        }
      }
      // row sums via MFMA against ones (accumulates ol; all cols identical)
#pragma unroll
      for (int qt = 0; qt < 4; ++qt)
        ol[qt] = __builtin_amdgcn_mfma_f32_16x16x32_bf16(
            __builtin_bit_cast(s8v, pai[qt]), ones, ol[qt], 0, 0, 0);
#pragma unroll
      for (int c = 0; c < 4; ++c) {
        s8v vf = *(const s8v*)(tb + 4096 + (kp * 4 + c) * 512);
#pragma unroll
        for (int qt = 0; qt < 4; ++qt)
          o[qt][c] = __builtin_amdgcn_mfma_f32_16x16x32_bf16(
              __builtin_bit_cast(s8v, pai[qt]), vf, o[qt][c], 0, 0, 0);
      }
    }
  }

  // store bf16 partials: pO[q][split][e] (merge-friendly), pL[q][split]
#pragma unroll
  for (int qt = 0; qt < 4; ++qt) {
#pragma unroll
    for (int r = 0; r < 4; ++r) {
      int q = qbase + qt * 16 + quad * 4 + r;
      short* dst = pO + (size_t)q * (SPLITS * DIM) + split * DIM;
#pragma unroll
      for (int c = 0; c < 4; ++c) dst[c * 16 + l15] = f2b(o[qt][c][r]);
      if (l15 == 0) pL[(size_t)q * SPLITS + split] = f2b(ol[qt][r]);
    }
  }
}

// ---------------- merge partials + output projection (fp32 out) -------------
__global__ __launch_bounds__(256) void merge_kernel(
    const short* __restrict__ pO, const short* __restrict__ pL,
    const float* __restrict__ wo, const float* __restrict__ bo,
    float* __restrict__ out) {
  __shared__ __align__(16) short wsh[DIM * KSTR];
  __shared__ __align__(16) float att[MROWS * DIM];
  int tid = threadIdx.x;
  int q0 = blockIdx.x * MROWS;
  for (int i = tid; i < DIM * 16; i += 256) {
    int r = i >> 4, c4 = (i & 15) << 2;
    float4 w = *(const float4*)&wo[r * DIM + c4];
    s4v p = {f2b(w.x), f2b(w.y), f2b(w.z), f2b(w.w)};
    *(s4v*)&wsh[r * KSTR + c4] = p;
  }
  int wave = tid >> 6, j = tid & 63;
  // phase 1: att rows, fully vectorized; lane j covers sp=j>>3 (+8), e8=j&7
#pragma unroll
  for (int i = 0; i < MROWS / 4; ++i) {
    int rr = wave * (MROWS / 4) + i;
    int q = q0 + rr;
    const short* prow = pO + (size_t)q * (SPLITS * DIM);
    s8v v0 = *(const s8v*)&prow[j * 8];
    s8v v1 = *(const s8v*)&prow[512 + j * 8];
    float a[8];
#pragma unroll
    for (int m = 0; m < 8; ++m) a[m] = b2f(v0[m]) + b2f(v1[m]);
#pragma unroll
    for (int st = 8; st < 64; st <<= 1)
#pragma unroll
      for (int m = 0; m < 8; ++m) a[m] += __shfl_xor(a[m], st);
    const short* lrow = pL + (size_t)q * SPLITS;
    s8v lv0 = *(const s8v*)&lrow[0];
    s8v lv1 = *(const s8v*)&lrow[8];
    float l = 0.f;
#pragma unroll
    for (int m = 0; m < 8; ++m) l += b2f(lv0[m]) + b2f(lv1[m]);
#if __has_builtin(__builtin_amdgcn_rcpf)
    float ri = __builtin_amdgcn_rcpf(l);
#else
    float ri = 1.f / l;
#endif
    if (j < 8) {
      float4 f0 = {a[0] * ri, a[1] * ri, a[2] * ri, a[3] * ri};
      float4 f1 = {a[4] * ri, a[5] * ri, a[6] * ri, a[7] * ri};
      *(float4*)&att[rr * DIM + j * 8] = f0;
      *(float4*)&att[rr * DIM + j * 8 + 4] = f1;
    }
  }
  __syncthreads();
  int e = tid & 63, rg = tid >> 6;
  for (int rr = rg; rr < MROWS; rr += 4) {
    float acc = bo[e];
#pragma unroll
    for (int c8 = 0; c8 < 8; ++c8) {
      s8v w = *(const s8v*)&wsh[e * KSTR + c8 * 8];
      const float* ar = &att[rr * DIM + c8 * 8];
      acc += ar[0] * b2f(w[0]) + ar[1] * b2f(w[1]) + ar[2] * b2f(w[2]) + ar[3] * b2f(w[3])
           + ar[4] * b2f(w[4]) + ar[5] * b2f(w[5]) + ar[6] * b2f(w[6]) + ar[7] * b2f(w[7]);
    }
    out[(size_t)(q0 + rr) * DIM + e] = acc;
  }
}

extern "C" void kernel_launch(void* const* d_in, const int* in_sizes, int n_in,
                              void* d_out, int out_size, void* d_ws, size_t ws_size,
                              hipStream_t stream) {
  const float* x  = (const float*)d_in[0];
  const float* wq = (const float*)d_in[1];
  const float* bq = (const float*)d_in[2];
  const float* wk = (const float*)d_in[3];
  const float* bk = (const float*)d_in[4];
  const float* wv = (const float*)d_in[5];
  const float* bv = (const float*)d_in[6];
  const float* th = (const float*)d_in[7];
  const float* wo = (const float*)d_in[8];
  const float* bo = (const float*)d_in[9];

  char* ws = (char*)d_ws;
  short* qq  = (short*)(ws);                            // 1 MB  (Q, row-major, SC2-scaled)
  short* kvT = (short*)(ws + (1u << 20));               // 2 MB  (K+V frag-tiled)
  short* pO  = (short*)(ws + (3u << 20));               // 16 MB bf16 partials [q][sp][e]
  short* pL  = (short*)(ws + (19u << 20));              // 256 KB bf16 sums [q][sp]

  hipLaunchKernelGGL(qkv_kernel, dim3(NQ / QKV_ROWS), dim3(QKV_TPB), 0, stream,
                     x, wq, bq, wk, bk, wv, bv, th, qq, kvT);
  hipLaunchKernelGGL(flash_kernel, dim3(GRID_FLASH), dim3(QBLK), 0, stream,
                     qq, kvT, pO, pL);
  hipLaunchKernelGGL(merge_kernel, dim3(MERGEB), dim3(256), 0, stream,
                     pO, pL, wo, bo, (float*)d_out);
}

// Round 3
// 117.830 us; speedup vs baseline: 1.1392x; 1.1392x over previous
//
#include <hip/hip_runtime.h>
#include <hip/hip_bf16.h>

// Problem constants
#define NQ 8192            // B*S flattened tokens
#define DIM 64             // embed dim
#define SPLITS 16          // key-dimension split (partials merged by kernel 3)
#define QBLK 128           // queries per block (2 waves x 64)
#define WQ 64              // queries per wave
#define BN 64              // keys per tile
#define KEYS_PER_SPLIT (NQ / SPLITS)       // 512
#define NTILES (KEYS_PER_SPLIT / BN)       // 8
#define GRID_FLASH ((NQ / QBLK) * SPLITS)  // 1024
#define MERGEB 512         // merge grid (2 blocks/CU)
#define MROWS (NQ / MERGEB)                // 16 rows per merge block
#define SC2 0.51012301920911057f           // (1/sqrt(8)) * log2(e), folded into qq
#define KSTR 72            // LDS row stride in shorts (merge weight tile)

typedef short s8v __attribute__((ext_vector_type(8)));   // 8 x bf16 bits
typedef short s4v __attribute__((ext_vector_type(4)));   // 4 x bf16 bits
typedef float f4v __attribute__((ext_vector_type(4)));
typedef int   i4v __attribute__((ext_vector_type(4)));

__device__ __forceinline__ float b2f(short s) {
  unsigned int u = ((unsigned int)(unsigned short)s) << 16;
  return __uint_as_float(u);
}
__device__ __forceinline__ short f2b(float f) {
  __hip_bfloat16 h = __float2bfloat16(f);
  return *reinterpret_cast<short*>(&h);
}
__device__ __forceinline__ int pack_bf16x2(float a, float b) {
  union { __hip_bfloat162 h; int i; } u;
  u.h = __float22bfloat162_rn(make_float2(a, b));
  return u.i;
}
__device__ __forceinline__ float fast_exp2(float x) {
#if __has_builtin(__builtin_amdgcn_exp2f)
  return __builtin_amdgcn_exp2f(x);   // single v_exp_f32, no OCML call
#else
  return exp2f(x);
#endif
}

// ---------------- prep: weights -> bf16 fragment-linear, biases, cos(theta) -
// wT[(mt*2+h)*512 + lane*8 + j] = Wstack[mt*16 + (lane&15)][h*32 + (lane>>4)*8 + j]
// where Wstack rows 0..63 = wq, 64..127 = wk, 128..191 = wv.
// bbs[192] = stacked biases (fp32), ctl[64] = cos(theta).
// Tiny (12288 elems); runs as one 256-thread block.
__global__ __launch_bounds__(256) void prep_kernel(
    const float* __restrict__ wq, const float* __restrict__ bq,
    const float* __restrict__ wk, const float* __restrict__ bk,
    const float* __restrict__ wv, const float* __restrict__ bv,
    const float* __restrict__ theta,
    short* __restrict__ wT, float* __restrict__ bbs, float* __restrict__ ctl) {
  int t = threadIdx.x;
#pragma unroll
  for (int i = 0; i < 6; ++i) {
    int g = t + 256 * i;             // s8v group 0..1535
    int c = g >> 6;                  // chunk = mt*2 + h
    int lane = g & 63;
    int mt = c >> 1, h = c & 1;
    int l15 = lane & 15, quad = lane >> 4;
    int srow = mt * 16 + l15;        // 0..191 stacked row
    int scol = h * 32 + quad * 8;
    const float* src = (srow < 64) ? (wq + srow * DIM)
                     : (srow < 128) ? (wk + (srow - 64) * DIM)
                                    : (wv + (srow - 128) * DIM);
    float4 a = *(const float4*)&src[scol];
    float4 b = *(const float4*)&src[scol + 4];
    s8v p = {f2b(a.x), f2b(a.y), f2b(a.z), f2b(a.w),
             f2b(b.x), f2b(b.y), f2b(b.z), f2b(b.w)};
    *(s8v*)&wT[g * 8] = p;
  }
  if (t < 192) bbs[t] = (t < 64) ? bq[t] : (t < 128) ? bk[t - 64] : bv[t - 128];
  if (t < 64) ctl[t] = __cosf(theta[t]);
}

// ---------------- QKV projection + quantum map (fp32 in, bf16 out) ----------
// One wave per block, grid (512 token-groups x 3 mt-groups) = 1536 blocks
// (6 blocks/CU, free-running: no LDS, no barriers). Each wave: one x B-frag
// (16 tokens), 4 output-tiles of its mt-group (Q / K / V), 8 MFMAs, cos
// epilogue on C fragments.
// kvT is FRAGMENT-LINEAR TILED (8192 shorts per 64-key tile: 8 K-chunks then
// 8 V-chunks of 512 = chunk*512 + lane*8 + j), so flash stages tiles with
// linear conflict-free DMA and reads fragments with zero repack. V chunks
// bake in the K=32 PV key permutation.
__global__ __launch_bounds__(64) void qkv_kernel(
    const float* __restrict__ x, const short* __restrict__ wT,
    const float* __restrict__ bbs, const float* __restrict__ ctl,
    short* __restrict__ qq, short* __restrict__ kvT) {
  int lane = threadIdx.x & 63;
  int l15 = lane & 15, quad = lane >> 4;
  int tg = blockIdx.x;     // token group (16 tokens)
  int mg = blockIdx.y;     // 0 = Q, 1 = K, 2 = V
  int n = tg * 16 + l15;   // this lane's token (as C column)

  // B-frag: X[token = l15][k = quad*8 + j], two k-halves (fp32 -> bf16)
  const float* xr = x + (size_t)n * DIM + quad * 8;
  float4 x0 = *(const float4*)&xr[0];
  float4 x1 = *(const float4*)&xr[4];
  float4 x2 = *(const float4*)&xr[32];
  float4 x3 = *(const float4*)&xr[36];
  s8v xf0 = {f2b(x0.x), f2b(x0.y), f2b(x0.z), f2b(x0.w),
             f2b(x1.x), f2b(x1.y), f2b(x1.z), f2b(x1.w)};
  s8v xf1 = {f2b(x2.x), f2b(x2.y), f2b(x2.z), f2b(x2.w),
             f2b(x3.x), f2b(x3.y), f2b(x3.z), f2b(x3.w)};

  size_t tb = (size_t)(n >> 6) * 8192;
  int nperm = (n & 3) | ((n & 16) >> 2);
  size_t vbase = tb + 4096 + ((n & 32) >> 5) * 2048 + ((n & 15) >> 2) * 128 + nperm;

#pragma unroll
  for (int i = 0; i < 4; ++i) {
    int mt = mg * 4 + i;
    // A-frag: Wstack[out-dim = mt*16 + l15][k = quad*8 + j], fragment-linear
    s8v wf0 = *(const s8v*)&wT[(mt * 2) * 512 + lane * 8];
    s8v wf1 = *(const s8v*)&wT[(mt * 2 + 1) * 512 + lane * 8];
    f4v acc = (f4v){0.f, 0.f, 0.f, 0.f};
    acc = __builtin_amdgcn_mfma_f32_16x16x32_bf16(wf0, xf0, acc, 0, 0, 0);
    acc = __builtin_amdgcn_mfma_f32_16x16x32_bf16(wf1, xf1, acc, 0, 0, 0);
    // C[row = out-dim = mt*16 + quad*4 + r][col = token = l15]
    int d0 = mt * 16 + quad * 4;
    float4 bias = *(const float4*)&bbs[d0];
    float4 ct4 = *(const float4*)&ctl[d0 & 63];
    float y0 = __cosf(acc[0] + bias.x) * ct4.x;
    float y1 = __cosf(acc[1] + bias.y) * ct4.y;
    float y2 = __cosf(acc[2] + bias.z) * ct4.z;
    float y3 = __cosf(acc[3] + bias.w) * ct4.w;
    if (mg == 0) {
      s4v p = {f2b(SC2 * y0), f2b(SC2 * y1), f2b(SC2 * y2), f2b(SC2 * y3)};
      *(s4v*)&qq[(size_t)n * DIM + d0] = p;
    } else if (mg == 1) {
      int e = d0 - 64;   // e&7 advances with r; higher fields constant over r
      size_t idx = tb + ((n & 63) >> 4) * 1024 + (e >> 5) * 512 +
                   ((e & 31) >> 3) * 128 + (n & 15) * 8 + (e & 7);
      s4v p = {f2b(y0), f2b(y1), f2b(y2), f2b(y3)};
      *(s4v*)&kvT[idx] = p;
    } else {
      int e0 = d0 - 128;
      float ys[4] = {y0, y1, y2, y3};
#pragma unroll
      for (int r = 0; r < 4; ++r) {
        int e = e0 + r;
        kvT[vbase + (e >> 4) * 512 + (e & 15) * 8] = f2b(ys[r]);
      }
    }
  }
}

// ---------------- Flash attention (no-max streaming softmax) ----------------
// |s| <= 64/sqrt(8) = 22.6 -> exp(s) <= 6.6e9, row sums <= 5.5e13: fp32-safe,
// so no running max; split partials merge by pure summation.
// QK computed as S^T (A=K, B=Q): exp'd C-regs are directly a PV A-operand.
// PV uses K=32 MFMA with the key-perm baked into kvT's V chunks.
// Row sums l computed by an extra MFMA against an all-ones B fragment (no
// VALU adds, no shuffles; l layout == o layout, all columns identical).
#if __has_builtin(__builtin_amdgcn_global_load_lds)
#define DMA_CHUNK(srcp, dstp) \
  __builtin_amdgcn_global_load_lds( \
      (const __attribute__((address_space(1))) void*)(srcp), \
      (__attribute__((address_space(3))) void*)(dstp), 16, 0, 0)
#else
#define DMA_CHUNK(srcp, dstp) \
  { *(s8v*)((short*)(dstp) + (threadIdx.x & 63) * 8) = \
        *(const s8v*)((const short*)(srcp)); }
#endif

__global__ __launch_bounds__(128, 2) void flash_kernel(
    const short* __restrict__ qq, const short* __restrict__ kvT,
    short* __restrict__ pO, short* __restrict__ pL) {
  __shared__ __align__(16) short lds[2][8192];  // dbuf: 8 K + 8 V chunks

  int tid = threadIdx.x;
  int wave = tid >> 6, lane = tid & 63;
  int l15 = lane & 15, quad = lane >> 4;
  int qblock = blockIdx.x >> 4, split = blockIdx.x & 15;
  int qbase = qblock * QBLK + wave * WQ;

  // Q B-frags: B[n=query=l15][k=dim=quad*8+j], two k-halves, 4 q-subtiles
  s8v qf[4][2];
#pragma unroll
  for (int qt = 0; qt < 4; ++qt) {
    const short* qr = qq + (qbase + qt * 16 + l15) * DIM + quad * 8;
    qf[qt][0] = *(const s8v*)qr;
    qf[qt][1] = *(const s8v*)(qr + 32);
  }

  const short ONE = (short)0x3F80;  // bf16 1.0
  const s8v ones = {ONE, ONE, ONE, ONE, ONE, ONE, ONE, ONE};

  f4v o[4][4], ol[4];
#pragma unroll
  for (int qt = 0; qt < 4; ++qt) {
    ol[qt] = (f4v){0.f, 0.f, 0.f, 0.f};
#pragma unroll
    for (int c = 0; c < 4; ++c) o[qt][c] = (f4v){0.f, 0.f, 0.f, 0.f};
  }

  int gt0 = split * NTILES;  // first global 64-key tile of this split

  // wave 0 stages the 8 K chunks, wave 1 the 8 V chunks (4 KB each wave)
#define STAGE(T, BUF)                                                        \
  {                                                                          \
    const short* s_ = kvT + (size_t)(gt0 + (T)) * 8192 + wave * 4096 +       \
                      lane * 8;                                              \
    short* d_ = &lds[BUF][wave * 4096];                                      \
    _Pragma("unroll") for (int c2 = 0; c2 < 8; ++c2)                         \
        DMA_CHUNK(s_ + c2 * 512, d_ + c2 * 512);                             \
  }

  STAGE(0, 0)

  for (int t = 0; t < NTILES; ++t) {
    __syncthreads();  // buf t&1 staged; buf (t+1)&1 fully consumed
    if (t + 1 < NTILES) STAGE(t + 1, (t + 1) & 1)

    const short* kb = lds[t & 1];
    const short* vb = lds[t & 1] + 4096;

#pragma unroll
    for (int kp = 0; kp < 2; ++kp) {   // pair of 16-key sub-tiles
      i4v pai[4];                      // exp'd P, A-operand bits, per qt
#pragma unroll
      for (int h = 0; h < 2; ++h) {
        int kt = kp * 2 + h;
        s8v kf0 = *(const s8v*)&kb[(kt * 2) * 512 + lane * 8];
        s8v kf1 = *(const s8v*)&kb[(kt * 2 + 1) * 512 + lane * 8];
#pragma unroll
        for (int qt = 0; qt < 4; ++qt) {
          f4v acc = (f4v){0.f, 0.f, 0.f, 0.f};
          acc = __builtin_amdgcn_mfma_f32_16x16x32_bf16(kf0, qf[qt][0], acc, 0, 0, 0);
          acc = __builtin_amdgcn_mfma_f32_16x16x32_bf16(kf1, qf[qt][1], acc, 0, 0, 0);
          // acc[r] = SC2*S^T[key=kt*16+quad*4+r][query=qt*16+l15]
          pai[qt][h * 2]     = pack_bf16x2(fast_exp2(acc[0]), fast_exp2(acc[1]));
          pai[qt][h * 2 + 1] = pack_bf16x2(fast_exp2(acc[2]), fast_exp2(acc[3]));
        }
      }
      // row sums via MFMA against ones (accumulates ol; all cols identical)
#pragma unroll
      for (int qt = 0; qt < 4; ++qt)
        ol[qt] = __builtin_amdgcn_mfma_f32_16x16x32_bf16(
            __builtin_bit_cast(s8v, pai[qt]), ones, ol[qt], 0, 0, 0);
#pragma unroll
      for (int c = 0; c < 4; ++c) {
        s8v vf = *(const s8v*)&vb[(kp * 4 + c) * 512 + lane * 8];
#pragma unroll
        for (int qt = 0; qt < 4; ++qt)
          o[qt][c] = __builtin_amdgcn_mfma_f32_16x16x32_bf16(
              __builtin_bit_cast(s8v, pai[qt]), vf, o[qt][c], 0, 0, 0);
      }
    }
  }

  // store bf16 partials: pO[q][split][e] (merge-friendly), pL[q][split]
#pragma unroll
  for (int qt = 0; qt < 4; ++qt) {
#pragma unroll
    for (int r = 0; r < 4; ++r) {
      int q = qbase + qt * 16 + quad * 4 + r;
      short* dst = pO + (size_t)q * (SPLITS * DIM) + split * DIM;
#pragma unroll
      for (int c = 0; c < 4; ++c) dst[c * 16 + l15] = f2b(o[qt][c][r]);
      if (l15 == 0) pL[(size_t)q * SPLITS + split] = f2b(ol[qt][r]);
    }
  }
}

// ---------------- merge partials + output projection (fp32 out) -------------
__global__ __launch_bounds__(256) void merge_kernel(
    const short* __restrict__ pO, const short* __restrict__ pL,
    const float* __restrict__ wo, const float* __restrict__ bo,
    float* __restrict__ out) {
  __shared__ __align__(16) short wsh[DIM * KSTR];
  __shared__ __align__(16) float att[MROWS * DIM];
  int tid = threadIdx.x;
  int q0 = blockIdx.x * MROWS;
  for (int i = tid; i < DIM * 16; i += 256) {
    int r = i >> 4, c4 = (i & 15) << 2;
    float4 w = *(const float4*)&wo[r * DIM + c4];
    s4v p = {f2b(w.x), f2b(w.y), f2b(w.z), f2b(w.w)};
    *(s4v*)&wsh[r * KSTR + c4] = p;
  }
  int wave = tid >> 6, j = tid & 63;
  // phase 1: att rows, fully vectorized; lane j covers sp=j>>3 (+8), e8=j&7
#pragma unroll
  for (int i = 0; i < MROWS / 4; ++i) {
    int rr = wave * (MROWS / 4) + i;
    int q = q0 + rr;
    const short* prow = pO + (size_t)q * (SPLITS * DIM);
    s8v v0 = *(const s8v*)&prow[j * 8];
    s8v v1 = *(const s8v*)&prow[512 + j * 8];
    float a[8];
#pragma unroll
    for (int m = 0; m < 8; ++m) a[m] = b2f(v0[m]) + b2f(v1[m]);
#pragma unroll
    for (int st = 8; st < 64; st <<= 1)
#pragma unroll
      for (int m = 0; m < 8; ++m) a[m] += __shfl_xor(a[m], st);
    const short* lrow = pL + (size_t)q * SPLITS;
    s8v lv0 = *(const s8v*)&lrow[0];
    s8v lv1 = *(const s8v*)&lrow[8];
    float l = 0.f;
#pragma unroll
    for (int m = 0; m < 8; ++m) l += b2f(lv0[m]) + b2f(lv1[m]);
#if __has_builtin(__builtin_amdgcn_rcpf)
    float ri = __builtin_amdgcn_rcpf(l);
#else
    float ri = 1.f / l;
#endif
    if (j < 8) {
      float4 f0 = {a[0] * ri, a[1] * ri, a[2] * ri, a[3] * ri};
      float4 f1 = {a[4] * ri, a[5] * ri, a[6] * ri, a[7] * ri};
      *(float4*)&att[rr * DIM + j * 8] = f0;
      *(float4*)&att[rr * DIM + j * 8 + 4] = f1;
    }
  }
  __syncthreads();
  int e = tid & 63, rg = tid >> 6;
  for (int rr = rg; rr < MROWS; rr += 4) {
    float acc = bo[e];
#pragma unroll
    for (int c8 = 0; c8 < 8; ++c8) {
      s8v w = *(const s8v*)&wsh[e * KSTR + c8 * 8];
      const float* ar = &att[rr * DIM + c8 * 8];
      acc += ar[0] * b2f(w[0]) + ar[1] * b2f(w[1]) + ar[2] * b2f(w[2]) + ar[3] * b2f(w[3])
           + ar[4] * b2f(w[4]) + ar[5] * b2f(w[5]) + ar[6] * b2f(w[6]) + ar[7] * b2f(w[7]);
    }
    out[(size_t)(q0 + rr) * DIM + e] = acc;
  }
}

extern "C" void kernel_launch(void* const* d_in, const int* in_sizes, int n_in,
                              void* d_out, int out_size, void* d_ws, size_t ws_size,
                              hipStream_t stream) {
  const float* x  = (const float*)d_in[0];
  const float* wq = (const float*)d_in[1];
  const float* bq = (const float*)d_in[2];
  const float* wk = (const float*)d_in[3];
  const float* bk = (const float*)d_in[4];
  const float* wv = (const float*)d_in[5];
  const float* bv = (const float*)d_in[6];
  const float* th = (const float*)d_in[7];
  const float* wo = (const float*)d_in[8];
  const float* bo = (const float*)d_in[9];

  char* ws = (char*)d_ws;
  short* qq  = (short*)(ws);                            // 1 MB  (Q, row-major, SC2-scaled)
  short* kvT = (short*)(ws + (1u << 20));               // 2 MB  (K+V frag-tiled)
  short* pO  = (short*)(ws + (3u << 20));               // 16 MB bf16 partials [q][sp][e]
  short* pL  = (short*)(ws + (19u << 20));              // 256 KB bf16 sums [q][sp]
  short* wT  = (short*)(ws + (20u << 20));              // 24 KB bf16 frag-linear weights
  float* bbs = (float*)(ws + (20u << 20) + (48u << 10));// 768 B stacked biases
  float* ctl = (float*)(ws + (20u << 20) + (52u << 10));// 256 B cos(theta)

  hipLaunchKernelGGL(prep_kernel, dim3(1), dim3(256), 0, stream,
                     wq, bq, wk, bk, wv, bv, th, wT, bbs, ctl);
  hipLaunchKernelGGL(qkv_kernel, dim3(NQ / 16, 3), dim3(64), 0, stream,
                     x, wT, bbs, ctl, qq, kvT);
  hipLaunchKernelGGL(flash_kernel, dim3(GRID_FLASH), dim3(128), 0, stream,
                     qq, kvT, pO, pL);
  hipLaunchKernelGGL(merge_kernel, dim3(MERGEB), dim3(256), 0, stream,
                     pO, pL, wo, bo, (float*)d_out);
}

// Round 4
// 115.269 us; speedup vs baseline: 1.1645x; 1.0222x over previous
//
#include <hip/hip_runtime.h>
#include <hip/hip_bf16.h>

// Problem constants
#define NQ 8192            // B*S flattened tokens
#define DIM 64             // embed dim
#define SPLITS 16          // key-dimension split (partials merged by kernel 3)
#define QBLK 128           // queries per block (2 waves x 64)
#define WQ 64              // queries per wave
#define BN 64              // keys per tile
#define KEYS_PER_SPLIT (NQ / SPLITS)       // 512
#define NTILES (KEYS_PER_SPLIT / BN)       // 8
#define GRID_FLASH ((NQ / QBLK) * SPLITS)  // 1024
#define MERGEB 512         // merge grid (2 blocks/CU)
#define MROWS (NQ / MERGEB)                // 16 rows per merge block
#define SC2 0.51012301920911057f           // (1/sqrt(8)) * log2(e), folded into qq
#define KSTR 72            // LDS row stride in shorts (merge weight tile)

typedef short s8v __attribute__((ext_vector_type(8)));   // 8 x bf16 bits
typedef short s4v __attribute__((ext_vector_type(4)));   // 4 x bf16 bits
typedef float f4v __attribute__((ext_vector_type(4)));
typedef int   i4v __attribute__((ext_vector_type(4)));

__device__ __forceinline__ float b2f(short s) {
  unsigned int u = ((unsigned int)(unsigned short)s) << 16;
  return __uint_as_float(u);
}
__device__ __forceinline__ short f2b(float f) {
  __hip_bfloat16 h = __float2bfloat16(f);
  return *reinterpret_cast<short*>(&h);
}
__device__ __forceinline__ int pack_bf16x2(float a, float b) {
  union { __hip_bfloat162 h; int i; } u;
  u.h = __float22bfloat162_rn(make_float2(a, b));
  return u.i;
}
__device__ __forceinline__ float fast_exp2(float x) {
#if __has_builtin(__builtin_amdgcn_exp2f)
  return __builtin_amdgcn_exp2f(x);   // single v_exp_f32, no OCML call
#else
  return exp2f(x);
#endif
}

// ---------------- QKV projection + quantum map (fp32 in, bf16 out) ----------
// One wave per block, grid (512 token-groups x 3 mt-groups) = 1536 blocks
// (6 blocks/CU, free-running: no LDS, no barriers, NO prep kernel). Each wave
// reads its W MFMA fragments DIRECTLY from the fp32 weight matrix (2 float4
// per fragment half; 16 KB per matrix -> L2-resident after first touch) and
// converts in-register. 8 MFMAs + cos epilogue on C fragments.
// kvT is FRAGMENT-LINEAR TILED (8192 shorts per 64-key tile: 8 K-chunks then
// 8 V-chunks of 512 = chunk*512 + lane*8 + j), so flash stages tiles with
// linear conflict-free DMA and reads fragments with zero repack. V chunks
// bake in the K=32 PV key permutation.
__global__ __launch_bounds__(64) void qkv_kernel(
    const float* __restrict__ x,
    const float* __restrict__ wq, const float* __restrict__ bq,
    const float* __restrict__ wk, const float* __restrict__ bk,
    const float* __restrict__ wv, const float* __restrict__ bv,
    const float* __restrict__ theta,
    short* __restrict__ qq, short* __restrict__ kvT) {
  int lane = threadIdx.x & 63;
  int l15 = lane & 15, quad = lane >> 4;
  int tg = blockIdx.x;     // token group (16 tokens)
  int mg = blockIdx.y;     // 0 = Q, 1 = K, 2 = V
  int n = tg * 16 + l15;   // this lane's token (as C column)

  const float* W  = (mg == 0) ? wq : (mg == 1) ? wk : wv;
  const float* Bb = (mg == 0) ? bq : (mg == 1) ? bk : bv;

  // B-frag: X[token = l15][k = quad*8 + j], two k-halves (fp32 -> bf16)
  const float* xr = x + (size_t)n * DIM + quad * 8;
  float4 x0 = *(const float4*)&xr[0];
  float4 x1 = *(const float4*)&xr[4];
  float4 x2 = *(const float4*)&xr[32];
  float4 x3 = *(const float4*)&xr[36];
  s8v xf0 = {f2b(x0.x), f2b(x0.y), f2b(x0.z), f2b(x0.w),
             f2b(x1.x), f2b(x1.y), f2b(x1.z), f2b(x1.w)};
  s8v xf1 = {f2b(x2.x), f2b(x2.y), f2b(x2.z), f2b(x2.w),
             f2b(x3.x), f2b(x3.y), f2b(x3.z), f2b(x3.w)};

  size_t tb = (size_t)(n >> 6) * 8192;
  int nperm = (n & 3) | ((n & 16) >> 2);
  size_t vbase = tb + 4096 + ((n & 32) >> 5) * 2048 + ((n & 15) >> 2) * 128 + nperm;

#pragma unroll
  for (int i = 0; i < 4; ++i) {
    // A-frag: W[out-dim = i*16 + l15][k = quad*8 + j], direct from fp32
    const float* wr = W + (size_t)(i * 16 + l15) * DIM + quad * 8;
    float4 a0 = *(const float4*)&wr[0];
    float4 a1 = *(const float4*)&wr[4];
    float4 a2 = *(const float4*)&wr[32];
    float4 a3 = *(const float4*)&wr[36];
    s8v wf0 = {f2b(a0.x), f2b(a0.y), f2b(a0.z), f2b(a0.w),
               f2b(a1.x), f2b(a1.y), f2b(a1.z), f2b(a1.w)};
    s8v wf1 = {f2b(a2.x), f2b(a2.y), f2b(a2.z), f2b(a2.w),
               f2b(a3.x), f2b(a3.y), f2b(a3.z), f2b(a3.w)};
    f4v acc = (f4v){0.f, 0.f, 0.f, 0.f};
    acc = __builtin_amdgcn_mfma_f32_16x16x32_bf16(wf0, xf0, acc, 0, 0, 0);
    acc = __builtin_amdgcn_mfma_f32_16x16x32_bf16(wf1, xf1, acc, 0, 0, 0);
    // C[row = out-dim = i*16 + quad*4 + r][col = token = l15], group-local
    int d0 = i * 16 + quad * 4;
    float4 bias = *(const float4*)&Bb[d0];
    float4 th4 = *(const float4*)&theta[d0];
    float y0 = __cosf(acc[0] + bias.x) * __cosf(th4.x);
    float y1 = __cosf(acc[1] + bias.y) * __cosf(th4.y);
    float y2 = __cosf(acc[2] + bias.z) * __cosf(th4.z);
    float y3 = __cosf(acc[3] + bias.w) * __cosf(th4.w);
    if (mg == 0) {
      s4v p = {f2b(SC2 * y0), f2b(SC2 * y1), f2b(SC2 * y2), f2b(SC2 * y3)};
      *(s4v*)&qq[(size_t)n * DIM + d0] = p;
    } else if (mg == 1) {
      int e = d0;        // e&7 advances with r; higher fields constant over r
      size_t idx = tb + ((n & 63) >> 4) * 1024 + (e >> 5) * 512 +
                   ((e & 31) >> 3) * 128 + (n & 15) * 8 + (e & 7);
      s4v p = {f2b(y0), f2b(y1), f2b(y2), f2b(y3)};
      *(s4v*)&kvT[idx] = p;
    } else {
      float ys[4] = {y0, y1, y2, y3};
#pragma unroll
      for (int r = 0; r < 4; ++r) {
        int e = d0 + r;
        kvT[vbase + (e >> 4) * 512 + (e & 15) * 8] = f2b(ys[r]);
      }
    }
  }
}

// ---------------- Flash attention (no-max streaming softmax) ----------------
// |s| <= 64/sqrt(8) = 22.6 -> exp(s) <= 6.6e9, row sums <= 5.5e13: fp32-safe,
// so no running max; split partials merge by pure summation.
// QK computed as S^T (A=K, B=Q): exp'd C-regs are directly a PV A-operand.
// PV uses K=32 MFMA with the key-perm baked into kvT's V chunks.
// Row sums l computed by an extra MFMA against an all-ones B fragment (no
// VALU adds, no shuffles; l layout == o layout, all columns identical).
#if __has_builtin(__builtin_amdgcn_global_load_lds)
#define DMA_CHUNK(srcp, dstp) \
  __builtin_amdgcn_global_load_lds( \
      (const __attribute__((address_space(1))) void*)(srcp), \
      (__attribute__((address_space(3))) void*)(dstp), 16, 0, 0)
#else
#define DMA_CHUNK(srcp, dstp) \
  { *(s8v*)((short*)(dstp) + (threadIdx.x & 63) * 8) = \
        *(const s8v*)((const short*)(srcp)); }
#endif

__global__ __launch_bounds__(128, 2) void flash_kernel(
    const short* __restrict__ qq, const short* __restrict__ kvT,
    short* __restrict__ pO, short* __restrict__ pL) {
  __shared__ __align__(16) short lds[2][8192];  // dbuf: 8 K + 8 V chunks

  int tid = threadIdx.x;
  int wave = tid >> 6, lane = tid & 63;
  int l15 = lane & 15, quad = lane >> 4;
  int qblock = blockIdx.x >> 4, split = blockIdx.x & 15;
  int qbase = qblock * QBLK + wave * WQ;

  // Q B-frags: B[n=query=l15][k=dim=quad*8+j], two k-halves, 4 q-subtiles
  s8v qf[4][2];
#pragma unroll
  for (int qt = 0; qt < 4; ++qt) {
    const short* qr = qq + (qbase + qt * 16 + l15) * DIM + quad * 8;
    qf[qt][0] = *(const s8v*)qr;
    qf[qt][1] = *(const s8v*)(qr + 32);
  }

  const short ONE = (short)0x3F80;  // bf16 1.0
  const s8v ones = {ONE, ONE, ONE, ONE, ONE, ONE, ONE, ONE};

  f4v o[4][4], ol[4];
#pragma unroll
  for (int qt = 0; qt < 4; ++qt) {
    ol[qt] = (f4v){0.f, 0.f, 0.f, 0.f};
#pragma unroll
    for (int c = 0; c < 4; ++c) o[qt][c] = (f4v){0.f, 0.f, 0.f, 0.f};
  }

  int gt0 = split * NTILES;  // first global 64-key tile of this split

  // wave 0 stages the 8 K chunks, wave 1 the 8 V chunks (4 KB each wave)
#define STAGE(T, BUF)                                                        \
  {                                                                          \
    const short* s_ = kvT + (size_t)(gt0 + (T)) * 8192 + wave * 4096 +       \
                      lane * 8;                                              \
    short* d_ = &lds[BUF][wave * 4096];                                      \
    _Pragma("unroll") for (int c2 = 0; c2 < 8; ++c2)                         \
        DMA_CHUNK(s_ + c2 * 512, d_ + c2 * 512);                             \
  }

  STAGE(0, 0)

  for (int t = 0; t < NTILES; ++t) {
    __syncthreads();  // buf t&1 staged; buf (t+1)&1 fully consumed
    if (t + 1 < NTILES) STAGE(t + 1, (t + 1) & 1)

    const short* kb = lds[t & 1];
    const short* vb = lds[t & 1] + 4096;

#pragma unroll
    for (int kp = 0; kp < 2; ++kp) {   // pair of 16-key sub-tiles
      i4v pai[4];                      // exp'd P, A-operand bits, per qt
#pragma unroll
      for (int h = 0; h < 2; ++h) {
        int kt = kp * 2 + h;
        s8v kf0 = *(const s8v*)&kb[(kt * 2) * 512 + lane * 8];
        s8v kf1 = *(const s8v*)&kb[(kt * 2 + 1) * 512 + lane * 8];
#pragma unroll
        for (int qt = 0; qt < 4; ++qt) {
          f4v acc = (f4v){0.f, 0.f, 0.f, 0.f};
          acc = __builtin_amdgcn_mfma_f32_16x16x32_bf16(kf0, qf[qt][0], acc, 0, 0, 0);
          acc = __builtin_amdgcn_mfma_f32_16x16x32_bf16(kf1, qf[qt][1], acc, 0, 0, 0);
          // acc[r] = SC2*S^T[key=kt*16+quad*4+r][query=qt*16+l15]
          pai[qt][h * 2]     = pack_bf16x2(fast_exp2(acc[0]), fast_exp2(acc[1]));
          pai[qt][h * 2 + 1] = pack_bf16x2(fast_exp2(acc[2]), fast_exp2(acc[3]));
        }
      }
      // row sums via MFMA against ones (accumulates ol; all cols identical)
#pragma unroll
      for (int qt = 0; qt < 4; ++qt)
        ol[qt] = __builtin_amdgcn_mfma_f32_16x16x32_bf16(
            __builtin_bit_cast(s8v, pai[qt]), ones, ol[qt], 0, 0, 0);
#pragma unroll
      for (int c = 0; c < 4; ++c) {
        s8v vf = *(const s8v*)&vb[(kp * 4 + c) * 512 + lane * 8];
#pragma unroll
        for (int qt = 0; qt < 4; ++qt)
          o[qt][c] = __builtin_amdgcn_mfma_f32_16x16x32_bf16(
              __builtin_bit_cast(s8v, pai[qt]), vf, o[qt][c], 0, 0, 0);
      }
    }
  }

  // store bf16 partials: pO[q][split][e] (merge-friendly), pL[q][split]
#pragma unroll
  for (int qt = 0; qt < 4; ++qt) {
#pragma unroll
    for (int r = 0; r < 4; ++r) {
      int q = qbase + qt * 16 + quad * 4 + r;
      short* dst = pO + (size_t)q * (SPLITS * DIM) + split * DIM;
#pragma unroll
      for (int c = 0; c < 4; ++c) dst[c * 16 + l15] = f2b(o[qt][c][r]);
      if (l15 == 0) pL[(size_t)q * SPLITS + split] = f2b(ol[qt][r]);
    }
  }
}

// ---------------- merge partials + output projection (fp32 out) -------------
__global__ __launch_bounds__(256) void merge_kernel(
    const short* __restrict__ pO, const short* __restrict__ pL,
    const float* __restrict__ wo, const float* __restrict__ bo,
    float* __restrict__ out) {
  __shared__ __align__(16) short wsh[DIM * KSTR];
  __shared__ __align__(16) float att[MROWS * DIM];
  int tid = threadIdx.x;
  int q0 = blockIdx.x * MROWS;
  for (int i = tid; i < DIM * 16; i += 256) {
    int r = i >> 4, c4 = (i & 15) << 2;
    float4 w = *(const float4*)&wo[r * DIM + c4];
    s4v p = {f2b(w.x), f2b(w.y), f2b(w.z), f2b(w.w)};
    *(s4v*)&wsh[r * KSTR + c4] = p;
  }
  int wave = tid >> 6, j = tid & 63;
  // phase 1: att rows, fully vectorized; lane j covers sp=j>>3 (+8), e8=j&7
#pragma unroll
  for (int i = 0; i < MROWS / 4; ++i) {
    int rr = wave * (MROWS / 4) + i;
    int q = q0 + rr;
    const short* prow = pO + (size_t)q * (SPLITS * DIM);
    s8v v0 = *(const s8v*)&prow[j * 8];
    s8v v1 = *(const s8v*)&prow[512 + j * 8];
    float a[8];
#pragma unroll
    for (int m = 0; m < 8; ++m) a[m] = b2f(v0[m]) + b2f(v1[m]);
#pragma unroll
    for (int st = 8; st < 64; st <<= 1)
#pragma unroll
      for (int m = 0; m < 8; ++m) a[m] += __shfl_xor(a[m], st);
    const short* lrow = pL + (size_t)q * SPLITS;
    s8v lv0 = *(const s8v*)&lrow[0];
    s8v lv1 = *(const s8v*)&lrow[8];
    float l = 0.f;
#pragma unroll
    for (int m = 0; m < 8; ++m) l += b2f(lv0[m]) + b2f(lv1[m]);
#if __has_builtin(__builtin_amdgcn_rcpf)
    float ri = __builtin_amdgcn_rcpf(l);
#else
    float ri = 1.f / l;
#endif
    if (j < 8) {
      float4 f0 = {a[0] * ri, a[1] * ri, a[2] * ri, a[3] * ri};
      float4 f1 = {a[4] * ri, a[5] * ri, a[6] * ri, a[7] * ri};
      *(float4*)&att[rr * DIM + j * 8] = f0;
      *(float4*)&att[rr * DIM + j * 8 + 4] = f1;
    }
  }
  __syncthreads();
  int e = tid & 63, rg = tid >> 6;
  for (int rr = rg; rr < MROWS; rr += 4) {
    float acc = bo[e];
#pragma unroll
    for (int c8 = 0; c8 < 8; ++c8) {
      s8v w = *(const s8v*)&wsh[e * KSTR + c8 * 8];
      const float* ar = &att[rr * DIM + c8 * 8];
      acc += ar[0] * b2f(w[0]) + ar[1] * b2f(w[1]) + ar[2] * b2f(w[2]) + ar[3] * b2f(w[3])
           + ar[4] * b2f(w[4]) + ar[5] * b2f(w[5]) + ar[6] * b2f(w[6]) + ar[7] * b2f(w[7]);
    }
    out[(size_t)(q0 + rr) * DIM + e] = acc;
  }
}

extern "C" void kernel_launch(void* const* d_in, const int* in_sizes, int n_in,
                              void* d_out, int out_size, void* d_ws, size_t ws_size,
                              hipStream_t stream) {
  const float* x  = (const float*)d_in[0];
  const float* wq = (const float*)d_in[1];
  const float* bq = (const float*)d_in[2];
  const float* wk = (const float*)d_in[3];
  const float* bk = (const float*)d_in[4];
  const float* wv = (const float*)d_in[5];
  const float* bv = (const float*)d_in[6];
  const float* th = (const float*)d_in[7];
  const float* wo = (const float*)d_in[8];
  const float* bo = (const float*)d_in[9];

  char* ws = (char*)d_ws;
  short* qq  = (short*)(ws);                            // 1 MB  (Q, row-major, SC2-scaled)
  short* kvT = (short*)(ws + (1u << 20));               // 2 MB  (K+V frag-tiled)
  short* pO  = (short*)(ws + (3u << 20));               // 16 MB bf16 partials [q][sp][e]
  short* pL  = (short*)(ws + (19u << 20));              // 256 KB bf16 sums [q][sp]

  hipLaunchKernelGGL(qkv_kernel, dim3(NQ / 16, 3), dim3(64), 0, stream,
                     x, wq, bq, wk, bk, wv, bv, th, qq, kvT);
  hipLaunchKernelGGL(flash_kernel, dim3(GRID_FLASH), dim3(128), 0, stream,
                     qq, kvT, pO, pL);
  hipLaunchKernelGGL(merge_kernel, dim3(MERGEB), dim3(256), 0, stream,
                     pO, pL, wo, bo, (float*)d_out);
}

// Round 5
// 114.728 us; speedup vs baseline: 1.1700x; 1.0047x over previous
//
#include <hip/hip_runtime.h>
#include <hip/hip_bf16.h>

// Problem constants
#define NQ 8192            // B*S flattened tokens
#define DIM 64             // embed dim
#define SPLITS 16          // key-dimension split (partials merged by kernel 3)
#define QBLK 128           // queries per block (2 waves x 64)
#define WQ 64              // queries per wave
#define BN 64              // keys per tile
#define KEYS_PER_SPLIT (NQ / SPLITS)       // 512
#define NTILES (KEYS_PER_SPLIT / BN)       // 8
#define GRID_FLASH ((NQ / QBLK) * SPLITS)  // 1024
#define MERGEB 1024        // merge grid (4 blocks/CU)
#define MROWS (NQ / MERGEB)                // 8 rows per merge block
#define SC2 0.51012301920911057f           // (1/sqrt(8)) * log2(e), folded into qq
#define KSTR 72            // LDS row stride in shorts (merge weight tile)

typedef short s8v __attribute__((ext_vector_type(8)));   // 8 x bf16 bits
typedef short s4v __attribute__((ext_vector_type(4)));   // 4 x bf16 bits
typedef float f4v __attribute__((ext_vector_type(4)));
typedef int   i4v __attribute__((ext_vector_type(4)));

__device__ __forceinline__ float b2f(short s) {
  unsigned int u = ((unsigned int)(unsigned short)s) << 16;
  return __uint_as_float(u);
}
__device__ __forceinline__ float b2f_lo(unsigned int u) {
  return __uint_as_float(u << 16);
}
__device__ __forceinline__ float b2f_hi(unsigned int u) {
  return __uint_as_float(u & 0xffff0000u);
}
__device__ __forceinline__ short f2b(float f) {
  __hip_bfloat16 h = __float2bfloat16(f);
  return *reinterpret_cast<short*>(&h);
}
__device__ __forceinline__ int pack_bf16x2(float a, float b) {
  union { __hip_bfloat162 h; int i; } u;
  u.h = __float22bfloat162_rn(make_float2(a, b));
  return u.i;
}
__device__ __forceinline__ float fast_exp2(float x) {
#if __has_builtin(__builtin_amdgcn_exp2f)
  return __builtin_amdgcn_exp2f(x);   // single v_exp_f32, no OCML call
#else
  return exp2f(x);
#endif
}

// ---------------- QKV projection + quantum map (fp32 in, bf16 out) ----------
// One wave per block, grid (512 token-groups x 3 mt-groups) = 1536 blocks
// (6 blocks/CU, free-running: no LDS, no barriers, NO prep kernel). Each wave
// reads its W MFMA fragments DIRECTLY from the fp32 weight matrix (2 float4
// per fragment half; 16 KB per matrix -> L2-resident after first touch) and
// converts in-register. 8 MFMAs + cos epilogue on C fragments.
// kvT is FRAGMENT-LINEAR TILED (8192 shorts per 64-key tile: 8 K-chunks then
// 8 V-chunks of 512 = chunk*512 + lane*8 + j), so flash stages tiles with
// linear conflict-free DMA and reads fragments with zero repack. V chunks
// bake in the K=32 PV key permutation.
__global__ __launch_bounds__(64) void qkv_kernel(
    const float* __restrict__ x,
    const float* __restrict__ wq, const float* __restrict__ bq,
    const float* __restrict__ wk, const float* __restrict__ bk,
    const float* __restrict__ wv, const float* __restrict__ bv,
    const float* __restrict__ theta,
    short* __restrict__ qq, short* __restrict__ kvT) {
  int lane = threadIdx.x & 63;
  int l15 = lane & 15, quad = lane >> 4;
  int tg = blockIdx.x;     // token group (16 tokens)
  int mg = blockIdx.y;     // 0 = Q, 1 = K, 2 = V
  int n = tg * 16 + l15;   // this lane's token (as C column)

  const float* W  = (mg == 0) ? wq : (mg == 1) ? wk : wv;
  const float* Bb = (mg == 0) ? bq : (mg == 1) ? bk : bv;

  // B-frag: X[token = l15][k = quad*8 + j], two k-halves (fp32 -> bf16)
  const float* xr = x + (size_t)n * DIM + quad * 8;
  float4 x0 = *(const float4*)&xr[0];
  float4 x1 = *(const float4*)&xr[4];
  float4 x2 = *(const float4*)&xr[32];
  float4 x3 = *(const float4*)&xr[36];
  s8v xf0 = {f2b(x0.x), f2b(x0.y), f2b(x0.z), f2b(x0.w),
             f2b(x1.x), f2b(x1.y), f2b(x1.z), f2b(x1.w)};
  s8v xf1 = {f2b(x2.x), f2b(x2.y), f2b(x2.z), f2b(x2.w),
             f2b(x3.x), f2b(x3.y), f2b(x3.z), f2b(x3.w)};

  size_t tb = (size_t)(n >> 6) * 8192;
  int nperm = (n & 3) | ((n & 16) >> 2);
  size_t vbase = tb + 4096 + ((n & 32) >> 5) * 2048 + ((n & 15) >> 2) * 128 + nperm;

#pragma unroll
  for (int i = 0; i < 4; ++i) {
    // A-frag: W[out-dim = i*16 + l15][k = quad*8 + j], direct from fp32
    const float* wr = W + (size_t)(i * 16 + l15) * DIM + quad * 8;
    float4 a0 = *(const float4*)&wr[0];
    float4 a1 = *(const float4*)&wr[4];
    float4 a2 = *(const float4*)&wr[32];
    float4 a3 = *(const float4*)&wr[36];
    s8v wf0 = {f2b(a0.x), f2b(a0.y), f2b(a0.z), f2b(a0.w),
               f2b(a1.x), f2b(a1.y), f2b(a1.z), f2b(a1.w)};
    s8v wf1 = {f2b(a2.x), f2b(a2.y), f2b(a2.z), f2b(a2.w),
               f2b(a3.x), f2b(a3.y), f2b(a3.z), f2b(a3.w)};
    f4v acc = (f4v){0.f, 0.f, 0.f, 0.f};
    acc = __builtin_amdgcn_mfma_f32_16x16x32_bf16(wf0, xf0, acc, 0, 0, 0);
    acc = __builtin_amdgcn_mfma_f32_16x16x32_bf16(wf1, xf1, acc, 0, 0, 0);
    // C[row = out-dim = i*16 + quad*4 + r][col = token = l15], group-local
    int d0 = i * 16 + quad * 4;
    float4 bias = *(const float4*)&Bb[d0];
    float4 th4 = *(const float4*)&theta[d0];
    float y0 = __cosf(acc[0] + bias.x) * __cosf(th4.x);
    float y1 = __cosf(acc[1] + bias.y) * __cosf(th4.y);
    float y2 = __cosf(acc[2] + bias.z) * __cosf(th4.z);
    float y3 = __cosf(acc[3] + bias.w) * __cosf(th4.w);
    if (mg == 0) {
      s4v p = {f2b(SC2 * y0), f2b(SC2 * y1), f2b(SC2 * y2), f2b(SC2 * y3)};
      *(s4v*)&qq[(size_t)n * DIM + d0] = p;
    } else if (mg == 1) {
      int e = d0;        // e&7 advances with r; higher fields constant over r
      size_t idx = tb + ((n & 63) >> 4) * 1024 + (e >> 5) * 512 +
                   ((e & 31) >> 3) * 128 + (n & 15) * 8 + (e & 7);
      s4v p = {f2b(y0), f2b(y1), f2b(y2), f2b(y3)};
      *(s4v*)&kvT[idx] = p;
    } else {
      float ys[4] = {y0, y1, y2, y3};
#pragma unroll
      for (int r = 0; r < 4; ++r) {
        int e = d0 + r;
        kvT[vbase + (e >> 4) * 512 + (e & 15) * 8] = f2b(ys[r]);
      }
    }
  }
}

// ---------------- Flash attention (no-max streaming softmax) ----------------
// |s| <= 64/sqrt(8) = 22.6 -> exp(s) <= 6.6e9, row sums <= 5.5e13: fp32-safe,
// so no running max; split partials merge by pure summation.
// QK computed as S^T (A=K, B=Q): exp'd C-regs are directly a PV A-operand.
// PV uses K=32 MFMA with the key-perm baked into kvT's V chunks.
// Row sums l computed by an extra MFMA against an all-ones B fragment (no
// VALU adds, no shuffles; l layout == o layout, all columns identical).
// T5: s_setprio(1) around the pure-MFMA cluster (ol + PV, 20 MFMAs).
#if __has_builtin(__builtin_amdgcn_global_load_lds)
#define DMA_CHUNK(srcp, dstp) \
  __builtin_amdgcn_global_load_lds( \
      (const __attribute__((address_space(1))) void*)(srcp), \
      (__attribute__((address_space(3))) void*)(dstp), 16, 0, 0)
#else
#define DMA_CHUNK(srcp, dstp) \
  { *(s8v*)((short*)(dstp) + (threadIdx.x & 63) * 8) = \
        *(const s8v*)((const short*)(srcp)); }
#endif

__global__ __launch_bounds__(128, 2) void flash_kernel(
    const short* __restrict__ qq, const short* __restrict__ kvT,
    short* __restrict__ pO, short* __restrict__ pL) {
  __shared__ __align__(16) short lds[2][8192];  // dbuf: 8 K + 8 V chunks

  int tid = threadIdx.x;
  int wave = tid >> 6, lane = tid & 63;
  int l15 = lane & 15, quad = lane >> 4;
  int qblock = blockIdx.x >> 4, split = blockIdx.x & 15;
  int qbase = qblock * QBLK + wave * WQ;

  // Q B-frags: B[n=query=l15][k=dim=quad*8+j], two k-halves, 4 q-subtiles
  s8v qf[4][2];
#pragma unroll
  for (int qt = 0; qt < 4; ++qt) {
    const short* qr = qq + (qbase + qt * 16 + l15) * DIM + quad * 8;
    qf[qt][0] = *(const s8v*)qr;
    qf[qt][1] = *(const s8v*)(qr + 32);
  }

  const short ONE = (short)0x3F80;  // bf16 1.0
  const s8v ones = {ONE, ONE, ONE, ONE, ONE, ONE, ONE, ONE};

  f4v o[4][4], ol[4];
#pragma unroll
  for (int qt = 0; qt < 4; ++qt) {
    ol[qt] = (f4v){0.f, 0.f, 0.f, 0.f};
#pragma unroll
    for (int c = 0; c < 4; ++c) o[qt][c] = (f4v){0.f, 0.f, 0.f, 0.f};
  }

  int gt0 = split * NTILES;  // first global 64-key tile of this split

  // wave 0 stages the 8 K chunks, wave 1 the 8 V chunks (4 KB each wave)
#define STAGE(T, BUF)                                                        \
  {                                                                          \
    const short* s_ = kvT + (size_t)(gt0 + (T)) * 8192 + wave * 4096 +       \
                      lane * 8;                                              \
    short* d_ = &lds[BUF][wave * 4096];                                      \
    _Pragma("unroll") for (int c2 = 0; c2 < 8; ++c2)                         \
        DMA_CHUNK(s_ + c2 * 512, d_ + c2 * 512);                             \
  }

  STAGE(0, 0)

  for (int t = 0; t < NTILES; ++t) {
    __syncthreads();  // buf t&1 staged; buf (t+1)&1 fully consumed
    if (t + 1 < NTILES) STAGE(t + 1, (t + 1) & 1)

    const short* kb = lds[t & 1];
    const short* vb = lds[t & 1] + 4096;

#pragma unroll
    for (int kp = 0; kp < 2; ++kp) {   // pair of 16-key sub-tiles
      i4v pai[4];                      // exp'd P, A-operand bits, per qt
#pragma unroll
      for (int h = 0; h < 2; ++h) {
        int kt = kp * 2 + h;
        s8v kf0 = *(const s8v*)&kb[(kt * 2) * 512 + lane * 8];
        s8v kf1 = *(const s8v*)&kb[(kt * 2 + 1) * 512 + lane * 8];
#pragma unroll
        for (int qt = 0; qt < 4; ++qt) {
          f4v acc = (f4v){0.f, 0.f, 0.f, 0.f};
          acc = __builtin_amdgcn_mfma_f32_16x16x32_bf16(kf0, qf[qt][0], acc, 0, 0, 0);
          acc = __builtin_amdgcn_mfma_f32_16x16x32_bf16(kf1, qf[qt][1], acc, 0, 0, 0);
          // acc[r] = SC2*S^T[key=kt*16+quad*4+r][query=qt*16+l15]
          pai[qt][h * 2]     = pack_bf16x2(fast_exp2(acc[0]), fast_exp2(acc[1]));
          pai[qt][h * 2 + 1] = pack_bf16x2(fast_exp2(acc[2]), fast_exp2(acc[3]));
        }
      }
      // pure-MFMA cluster: row sums + PV (T5: favor this wave while it issues)
      __builtin_amdgcn_s_setprio(1);
#pragma unroll
      for (int qt = 0; qt < 4; ++qt)
        ol[qt] = __builtin_amdgcn_mfma_f32_16x16x32_bf16(
            __builtin_bit_cast(s8v, pai[qt]), ones, ol[qt], 0, 0, 0);
#pragma unroll
      for (int c = 0; c < 4; ++c) {
        s8v vf = *(const s8v*)&vb[(kp * 4 + c) * 512 + lane * 8];
#pragma unroll
        for (int qt = 0; qt < 4; ++qt)
          o[qt][c] = __builtin_amdgcn_mfma_f32_16x16x32_bf16(
              __builtin_bit_cast(s8v, pai[qt]), vf, o[qt][c], 0, 0, 0);
      }
      __builtin_amdgcn_s_setprio(0);
    }
  }

  // store bf16 partials: pO[split][q][e] (merge reads per-lane over sp, no
  // shuffles), pL[split][q]
#pragma unroll
  for (int qt = 0; qt < 4; ++qt) {
#pragma unroll
    for (int r = 0; r < 4; ++r) {
      int q = qbase + qt * 16 + quad * 4 + r;
      short* dst = pO + ((size_t)split * NQ + q) * DIM;
#pragma unroll
      for (int c = 0; c < 4; ++c) dst[c * 16 + l15] = f2b(o[qt][c][r]);
      if (l15 == 0) pL[(size_t)split * NQ + q] = f2b(ol[qt][r]);
    }
  }
}

// ---------------- merge partials + output projection (fp32 out) -------------
// pO[sp][q][e]: the split-sum is a per-lane serial loop of 16 coalesced dword
// loads (16-deep MLP, no shuffles, no idle lanes). Grid 1024 = 4 blocks/CU.
__global__ __launch_bounds__(256) void merge_kernel(
    const short* __restrict__ pO, const short* __restrict__ pL,
    const float* __restrict__ wo, const float* __restrict__ bo,
    float* __restrict__ out) {
  __shared__ __align__(16) short wsh[DIM * KSTR];
  __shared__ __align__(16) float att[MROWS * DIM];
  int tid = threadIdx.x;
  int q0 = blockIdx.x * MROWS;
  for (int i = tid; i < DIM * 16; i += 256) {
    int r = i >> 4, c4 = (i & 15) << 2;
    float4 w = *(const float4*)&wo[r * DIM + c4];
    s4v p = {f2b(w.x), f2b(w.y), f2b(w.z), f2b(w.w)};
    *(s4v*)&wsh[r * KSTR + c4] = p;
  }
  // phase 1: thread owns (row = tid>>5, e-pair = (tid&31)*2); 8 rows x 64 e
  {
    int e2 = (tid & 31) * 2, rg8 = tid >> 5;
    int q = q0 + rg8;
    const short* psrc = pO + (size_t)q * DIM + e2;
    const short* lsrc = pL + q;
    float a0 = 0.f, a1 = 0.f, l = 0.f;
#pragma unroll
    for (int sp = 0; sp < SPLITS; ++sp) {
      unsigned int u = *(const unsigned int*)&psrc[(size_t)sp * NQ * DIM];
      a0 += b2f_lo(u);
      a1 += b2f_hi(u);
      l += b2f(lsrc[(size_t)sp * NQ]);
    }
#if __has_builtin(__builtin_amdgcn_rcpf)
    float ri = __builtin_amdgcn_rcpf(l);
#else
    float ri = 1.f / l;
#endif
    att[rg8 * DIM + e2] = a0 * ri;
    att[rg8 * DIM + e2 + 1] = a1 * ri;
  }
  __syncthreads();
  // phase 2: out = att @ wo^T + bo
  int e = tid & 63, rg = tid >> 6;
  for (int rr = rg; rr < MROWS; rr += 4) {
    float acc = bo[e];
#pragma unroll
    for (int c8 = 0; c8 < 8; ++c8) {
      s8v w = *(const s8v*)&wsh[e * KSTR + c8 * 8];
      const float* ar = &att[rr * DIM + c8 * 8];
      acc += ar[0] * b2f(w[0]) + ar[1] * b2f(w[1]) + ar[2] * b2f(w[2]) + ar[3] * b2f(w[3])
           + ar[4] * b2f(w[4]) + ar[5] * b2f(w[5]) + ar[6] * b2f(w[6]) + ar[7] * b2f(w[7]);
    }
    out[(size_t)(q0 + rr) * DIM + e] = acc;
  }
}

extern "C" void kernel_launch(void* const* d_in, const int* in_sizes, int n_in,
                              void* d_out, int out_size, void* d_ws, size_t ws_size,
                              hipStream_t stream) {
  const float* x  = (const float*)d_in[0];
  const float* wq = (const float*)d_in[1];
  const float* bq = (const float*)d_in[2];
  const float* wk = (const float*)d_in[3];
  const float* bk = (const float*)d_in[4];
  const float* wv = (const float*)d_in[5];
  const float* bv = (const float*)d_in[6];
  const float* th = (const float*)d_in[7];
  const float* wo = (const float*)d_in[8];
  const float* bo = (const float*)d_in[9];

  char* ws = (char*)d_ws;
  short* qq  = (short*)(ws);                            // 1 MB  (Q, row-major, SC2-scaled)
  short* kvT = (short*)(ws + (1u << 20));               // 2 MB  (K+V frag-tiled)
  short* pO  = (short*)(ws + (3u << 20));               // 16 MB bf16 partials [sp][q][e]
  short* pL  = (short*)(ws + (19u << 20));              // 256 KB bf16 sums [sp][q]

  hipLaunchKernelGGL(qkv_kernel, dim3(NQ / 16, 3), dim3(64), 0, stream,
                     x, wq, bq, wk, bk, wv, bv, th, qq, kvT);
  hipLaunchKernelGGL(flash_kernel, dim3(GRID_FLASH), dim3(128), 0, stream,
                     qq, kvT, pO, pL);
  hipLaunchKernelGGL(merge_kernel, dim3(MERGEB), dim3(256), 0, stream,
                     pO, pL, wo, bo, (float*)d_out);
}

// Round 6
// 112.905 us; speedup vs baseline: 1.1889x; 1.0161x over previous
//
#include <hip/hip_runtime.h>
#include <hip/hip_bf16.h>

// Problem constants
#define NQ 8192            // B*S flattened tokens
#define DIM 64             // embed dim
#define SPLITS 16          // key-dimension split (partials merged by kernel 3)
#define FQB 64             // queries per flash block = ONE wave
#define KEYS_PER_SPLIT (NQ / SPLITS)       // 512
#define NSTEPS (KEYS_PER_SPLIT / 32)       // 16 x 32-key steps
#define GRID_FLASH ((NQ / FQB) * SPLITS)   // 2048
#define MERGEB 1024        // merge grid (4 blocks/CU)
#define MROWS (NQ / MERGEB)                // 8 rows per merge block
#define SC2 0.51012301920911057f           // (1/sqrt(8)) * log2(e), folded into qq
#define KSTR 72            // LDS row stride in shorts (merge weight tile)

typedef short s8v __attribute__((ext_vector_type(8)));   // 8 x bf16 bits
typedef short s4v __attribute__((ext_vector_type(4)));   // 4 x bf16 bits
typedef float f4v __attribute__((ext_vector_type(4)));
typedef int   i4v __attribute__((ext_vector_type(4)));

__device__ __forceinline__ float b2f(short s) {
  unsigned int u = ((unsigned int)(unsigned short)s) << 16;
  return __uint_as_float(u);
}
__device__ __forceinline__ float b2f_lo(unsigned int u) {
  return __uint_as_float(u << 16);
}
__device__ __forceinline__ float b2f_hi(unsigned int u) {
  return __uint_as_float(u & 0xffff0000u);
}
__device__ __forceinline__ short f2b(float f) {
  __hip_bfloat16 h = __float2bfloat16(f);
  return *reinterpret_cast<short*>(&h);
}
__device__ __forceinline__ int pack_bf16x2(float a, float b) {
  union { __hip_bfloat162 h; int i; } u;
  u.h = __float22bfloat162_rn(make_float2(a, b));
  return u.i;
}
__device__ __forceinline__ float fast_exp2(float x) {
#if __has_builtin(__builtin_amdgcn_exp2f)
  return __builtin_amdgcn_exp2f(x);   // single v_exp_f32, no OCML call
#else
  return exp2f(x);
#endif
}

// ---------------- QKV projection + quantum map (fp32 in, bf16 out) ----------
// One wave per block, grid (512 token-groups x 3 mt-groups) = 1536 blocks
// (6 blocks/CU, free-running: no LDS, no barriers, NO prep kernel). Each wave
// reads its W MFMA fragments DIRECTLY from the fp32 weight matrix (2 float4
// per fragment half; 16 KB per matrix -> L2-resident after first touch) and
// converts in-register. 8 MFMAs + cos epilogue on C fragments.
// kvT is FRAGMENT-LINEAR TILED (8192 shorts per 64-key tile: 8 K-chunks then
// 8 V-chunks of 512 = chunk*512 + lane*8 + j), so flash stages sub-tiles with
// linear conflict-free DMA and reads fragments with zero repack. V chunks
// bake in the K=32 PV key permutation.
__global__ __launch_bounds__(64) void qkv_kernel(
    const float* __restrict__ x,
    const float* __restrict__ wq, const float* __restrict__ bq,
    const float* __restrict__ wk, const float* __restrict__ bk,
    const float* __restrict__ wv, const float* __restrict__ bv,
    const float* __restrict__ theta,
    short* __restrict__ qq, short* __restrict__ kvT) {
  int lane = threadIdx.x & 63;
  int l15 = lane & 15, quad = lane >> 4;
  int tg = blockIdx.x;     // token group (16 tokens)
  int mg = blockIdx.y;     // 0 = Q, 1 = K, 2 = V
  int n = tg * 16 + l15;   // this lane's token (as C column)

  const float* W  = (mg == 0) ? wq : (mg == 1) ? wk : wv;
  const float* Bb = (mg == 0) ? bq : (mg == 1) ? bk : bv;

  // B-frag: X[token = l15][k = quad*8 + j], two k-halves (fp32 -> bf16)
  const float* xr = x + (size_t)n * DIM + quad * 8;
  float4 x0 = *(const float4*)&xr[0];
  float4 x1 = *(const float4*)&xr[4];
  float4 x2 = *(const float4*)&xr[32];
  float4 x3 = *(const float4*)&xr[36];
  s8v xf0 = {f2b(x0.x), f2b(x0.y), f2b(x0.z), f2b(x0.w),
             f2b(x1.x), f2b(x1.y), f2b(x1.z), f2b(x1.w)};
  s8v xf1 = {f2b(x2.x), f2b(x2.y), f2b(x2.z), f2b(x2.w),
             f2b(x3.x), f2b(x3.y), f2b(x3.z), f2b(x3.w)};

  size_t tb = (size_t)(n >> 6) * 8192;
  int nperm = (n & 3) | ((n & 16) >> 2);
  size_t vbase = tb + 4096 + ((n & 32) >> 5) * 2048 + ((n & 15) >> 2) * 128 + nperm;

#pragma unroll
  for (int i = 0; i < 4; ++i) {
    // A-frag: W[out-dim = i*16 + l15][k = quad*8 + j], direct from fp32
    const float* wr = W + (size_t)(i * 16 + l15) * DIM + quad * 8;
    float4 a0 = *(const float4*)&wr[0];
    float4 a1 = *(const float4*)&wr[4];
    float4 a2 = *(const float4*)&wr[32];
    float4 a3 = *(const float4*)&wr[36];
    s8v wf0 = {f2b(a0.x), f2b(a0.y), f2b(a0.z), f2b(a0.w),
               f2b(a1.x), f2b(a1.y), f2b(a1.z), f2b(a1.w)};
    s8v wf1 = {f2b(a2.x), f2b(a2.y), f2b(a2.z), f2b(a2.w),
               f2b(a3.x), f2b(a3.y), f2b(a3.z), f2b(a3.w)};
    f4v acc = (f4v){0.f, 0.f, 0.f, 0.f};
    acc = __builtin_amdgcn_mfma_f32_16x16x32_bf16(wf0, xf0, acc, 0, 0, 0);
    acc = __builtin_amdgcn_mfma_f32_16x16x32_bf16(wf1, xf1, acc, 0, 0, 0);
    // C[row = out-dim = i*16 + quad*4 + r][col = token = l15], group-local
    int d0 = i * 16 + quad * 4;
    float4 bias = *(const float4*)&Bb[d0];
    float4 th4 = *(const float4*)&theta[d0];
    float y0 = __cosf(acc[0] + bias.x) * __cosf(th4.x);
    float y1 = __cosf(acc[1] + bias.y) * __cosf(th4.y);
    float y2 = __cosf(acc[2] + bias.z) * __cosf(th4.z);
    float y3 = __cosf(acc[3] + bias.w) * __cosf(th4.w);
    if (mg == 0) {
      s4v p = {f2b(SC2 * y0), f2b(SC2 * y1), f2b(SC2 * y2), f2b(SC2 * y3)};
      *(s4v*)&qq[(size_t)n * DIM + d0] = p;
    } else if (mg == 1) {
      int e = d0;        // e&7 advances with r; higher fields constant over r
      size_t idx = tb + ((n & 63) >> 4) * 1024 + (e >> 5) * 512 +
                   ((e & 31) >> 3) * 128 + (n & 15) * 8 + (e & 7);
      s4v p = {f2b(y0), f2b(y1), f2b(y2), f2b(y3)};
      *(s4v*)&kvT[idx] = p;
    } else {
      float ys[4] = {y0, y1, y2, y3};
#pragma unroll
      for (int r = 0; r < 4; ++r) {
        int e = d0 + r;
        kvT[vbase + (e >> 4) * 512 + (e & 15) * 8] = f2b(ys[r]);
      }
    }
  }
}

// ---------------- Flash attention (no-max streaming softmax) ----------------
// |s| <= 64/sqrt(8) = 22.6 -> exp(s) <= 6.6e9, row sums <= 5.5e13: fp32-safe,
// so no running max; split partials merge by pure summation.
// QK computed as S^T (A=K, B=Q): exp'd C-regs are directly a PV A-operand.
// PV uses K=32 MFMA with the key-perm baked into kvT's V chunks.
// Row sums l computed by an extra MFMA against an all-ones B fragment.
//
// SINGLE-WAVE BLOCKS, ZERO BARRIERS: each wave stages its own 32-key step
// (8 KB: 4 K chunks + 4 V chunks) into a wave-private LDS double buffer via
// global_load_lds, pipelined with COUNTED s_waitcnt vmcnt(8) (T4: step s+1's
// 8 chunks stay in flight while step s computes; never drain to 0 in-loop).
// vmcnt is wave-local so no cross-wave hazard exists; qf loads are drained
// once up front so the vmcnt ledger counts DMA chunks only. 16 KB LDS/block
// -> 8 one-wave blocks/CU co-resident (grid 2048), all free-running.
#if __has_builtin(__builtin_amdgcn_global_load_lds)
#define DMA_CHUNK(srcp, dstp) \
  __builtin_amdgcn_global_load_lds( \
      (const __attribute__((address_space(1))) void*)(srcp), \
      (__attribute__((address_space(3))) void*)(dstp), 16, 0, 0)
#else
#define DMA_CHUNK(srcp, dstp) \
  { *(s8v*)((short*)(dstp) + (threadIdx.x & 63) * 8) = \
        *(const s8v*)((const short*)(srcp)); }
#endif

__global__ __launch_bounds__(64, 2) void flash_kernel(
    const short* __restrict__ qq, const short* __restrict__ kvT,
    short* __restrict__ pO, short* __restrict__ pL) {
  __shared__ __align__(16) short lds[2][4096];  // dbuf: 4 K + 4 V chunks each

  int lane = threadIdx.x & 63;
  int l15 = lane & 15, quad = lane >> 4;
  int qblock = blockIdx.x >> 4, split = blockIdx.x & 15;
  int qbase = qblock * FQB;

  // Q B-frags: B[n=query=l15][k=dim=quad*8+j], two k-halves, 4 q-subtiles
  s8v qf[4][2];
#pragma unroll
  for (int qt = 0; qt < 4; ++qt) {
    const short* qr = qq + (qbase + qt * 16 + l15) * DIM + quad * 8;
    qf[qt][0] = *(const s8v*)qr;
    qf[qt][1] = *(const s8v*)(qr + 32);
  }
  // retire qf loads so the vmcnt ledger below counts ONLY DMA chunks
  asm volatile("s_waitcnt vmcnt(0)" ::: "memory");

  const short ONE = (short)0x3F80;  // bf16 1.0
  const s8v ones = {ONE, ONE, ONE, ONE, ONE, ONE, ONE, ONE};

  f4v o[4][4], ol[4];
#pragma unroll
  for (int qt = 0; qt < 4; ++qt) {
    ol[qt] = (f4v){0.f, 0.f, 0.f, 0.f};
#pragma unroll
    for (int c = 0; c < 4; ++c) o[qt][c] = (f4v){0.f, 0.f, 0.f, 0.f};
  }

  // 32-key step S of this split: 64-key tile gt0 + (S>>1), half S&1.
  // K chunks [4*(S&1)..+3] at tile base; V chunks same indices at +4096.
  const short* kvs = kvT + (size_t)(split * (KEYS_PER_SPLIT / 64)) * 8192 +
                     lane * 8;
#define STAGE32(S, BUF)                                                      \
  {                                                                          \
    const short* s_ = kvs + ((S) >> 1) * 8192 + ((S) & 1) * 2048;            \
    short* d_ = &lds[BUF][0];                                                \
    _Pragma("unroll") for (int c2 = 0; c2 < 4; ++c2) {                       \
      DMA_CHUNK(s_ + c2 * 512, d_ + c2 * 512);                               \
      DMA_CHUNK(s_ + 4096 + c2 * 512, d_ + 2048 + c2 * 512);                 \
    }                                                                        \
  }

  STAGE32(0, 0)

  for (int s = 0; s < NSTEPS; ++s) {
    if (s + 1 < NSTEPS) {
      STAGE32(s + 1, (s + 1) & 1)
      // outstanding = 16 (step s + step s+1); wait for step s's 8 only
      asm volatile("s_waitcnt vmcnt(8)" ::: "memory");
    } else {
      asm volatile("s_waitcnt vmcnt(0)" ::: "memory");
    }
    __builtin_amdgcn_sched_barrier(0);

    const short* kb = lds[s & 1];
    const short* vb = kb + 2048;

    i4v pai[4];                      // exp'd P over these 32 keys, per qt
#pragma unroll
    for (int h = 0; h < 2; ++h) {    // 16-key sub-tile within the step
      s8v kf0 = *(const s8v*)&kb[(h * 2) * 512 + lane * 8];
      s8v kf1 = *(const s8v*)&kb[(h * 2 + 1) * 512 + lane * 8];
#pragma unroll
      for (int qt = 0; qt < 4; ++qt) {
        f4v acc = (f4v){0.f, 0.f, 0.f, 0.f};
        acc = __builtin_amdgcn_mfma_f32_16x16x32_bf16(kf0, qf[qt][0], acc, 0, 0, 0);
        acc = __builtin_amdgcn_mfma_f32_16x16x32_bf16(kf1, qf[qt][1], acc, 0, 0, 0);
        // acc[r] = SC2*S^T[key=h*16+quad*4+r][query=qt*16+l15]
        pai[qt][h * 2]     = pack_bf16x2(fast_exp2(acc[0]), fast_exp2(acc[1]));
        pai[qt][h * 2 + 1] = pack_bf16x2(fast_exp2(acc[2]), fast_exp2(acc[3]));
      }
    }
    // pure-MFMA cluster: row sums + PV (T5)
    __builtin_amdgcn_s_setprio(1);
#pragma unroll
    for (int qt = 0; qt < 4; ++qt)
      ol[qt] = __builtin_amdgcn_mfma_f32_16x16x32_bf16(
          __builtin_bit_cast(s8v, pai[qt]), ones, ol[qt], 0, 0, 0);
#pragma unroll
    for (int c = 0; c < 4; ++c) {
      s8v vf = *(const s8v*)&vb[c * 512 + lane * 8];
#pragma unroll
      for (int qt = 0; qt < 4; ++qt)
        o[qt][c] = __builtin_amdgcn_mfma_f32_16x16x32_bf16(
            __builtin_bit_cast(s8v, pai[qt]), vf, o[qt][c], 0, 0, 0);
    }
    __builtin_amdgcn_s_setprio(0);
  }

  // store bf16 partials: pO[split][q][e] (merge reads per-lane over sp, no
  // shuffles), pL[split][q]
#pragma unroll
  for (int qt = 0; qt < 4; ++qt) {
#pragma unroll
    for (int r = 0; r < 4; ++r) {
      int q = qbase + qt * 16 + quad * 4 + r;
      short* dst = pO + ((size_t)split * NQ + q) * DIM;
#pragma unroll
      for (int c = 0; c < 4; ++c) dst[c * 16 + l15] = f2b(o[qt][c][r]);
      if (l15 == 0) pL[(size_t)split * NQ + q] = f2b(ol[qt][r]);
    }
  }
}

// ---------------- merge partials + output projection (fp32 out) -------------
// pO[sp][q][e]: the split-sum is a per-lane serial loop of 16 coalesced dword
// loads (16-deep MLP, no shuffles, no idle lanes). Grid 1024 = 4 blocks/CU.
__global__ __launch_bounds__(256) void merge_kernel(
    const short* __restrict__ pO, const short* __restrict__ pL,
    const float* __restrict__ wo, const float* __restrict__ bo,
    float* __restrict__ out) {
  __shared__ __align__(16) short wsh[DIM * KSTR];
  __shared__ __align__(16) float att[MROWS * DIM];
  int tid = threadIdx.x;
  int q0 = blockIdx.x * MROWS;
  for (int i = tid; i < DIM * 16; i += 256) {
    int r = i >> 4, c4 = (i & 15) << 2;
    float4 w = *(const float4*)&wo[r * DIM + c4];
    s4v p = {f2b(w.x), f2b(w.y), f2b(w.z), f2b(w.w)};
    *(s4v*)&wsh[r * KSTR + c4] = p;
  }
  // phase 1: thread owns (row = tid>>5, e-pair = (tid&31)*2); 8 rows x 64 e
  {
    int e2 = (tid & 31) * 2, rg8 = tid >> 5;
    int q = q0 + rg8;
    const short* psrc = pO + (size_t)q * DIM + e2;
    const short* lsrc = pL + q;
    float a0 = 0.f, a1 = 0.f, l = 0.f;
#pragma unroll
    for (int sp = 0; sp < SPLITS; ++sp) {
      unsigned int u = *(const unsigned int*)&psrc[(size_t)sp * NQ * DIM];
      a0 += b2f_lo(u);
      a1 += b2f_hi(u);
      l += b2f(lsrc[(size_t)sp * NQ]);
    }
#if __has_builtin(__builtin_amdgcn_rcpf)
    float ri = __builtin_amdgcn_rcpf(l);
#else
    float ri = 1.f / l;
#endif
    att[rg8 * DIM + e2] = a0 * ri;
    att[rg8 * DIM + e2 + 1] = a1 * ri;
  }
  __syncthreads();
  // phase 2: out = att @ wo^T + bo
  int e = tid & 63, rg = tid >> 6;
  for (int rr = rg; rr < MROWS; rr += 4) {
    float acc = bo[e];
#pragma unroll
    for (int c8 = 0; c8 < 8; ++c8) {
      s8v w = *(const s8v*)&wsh[e * KSTR + c8 * 8];
      const float* ar = &att[rr * DIM + c8 * 8];
      acc += ar[0] * b2f(w[0]) + ar[1] * b2f(w[1]) + ar[2] * b2f(w[2]) + ar[3] * b2f(w[3])
           + ar[4] * b2f(w[4]) + ar[5] * b2f(w[5]) + ar[6] * b2f(w[6]) + ar[7] * b2f(w[7]);
    }
    out[(size_t)(q0 + rr) * DIM + e] = acc;
  }
}

extern "C" void kernel_launch(void* const* d_in, const int* in_sizes, int n_in,
                              void* d_out, int out_size, void* d_ws, size_t ws_size,
                              hipStream_t stream) {
  const float* x  = (const float*)d_in[0];
  const float* wq = (const float*)d_in[1];
  const float* bq = (const float*)d_in[2];
  const float* wk = (const float*)d_in[3];
  const float* bk = (const float*)d_in[4];
  const float* wv = (const float*)d_in[5];
  const float* bv = (const float*)d_in[6];
  const float* th = (const float*)d_in[7];
  const float* wo = (const float*)d_in[8];
  const float* bo = (const float*)d_in[9];

  char* ws = (char*)d_ws;
  short* qq  = (short*)(ws);                            // 1 MB  (Q, row-major, SC2-scaled)
  short* kvT = (short*)(ws + (1u << 20));               // 2 MB  (K+V frag-tiled)
  short* pO  = (short*)(ws + (3u << 20));               // 16 MB bf16 partials [sp][q][e]
  short* pL  = (short*)(ws + (19u << 20));              // 256 KB bf16 sums [sp][q]

  hipLaunchKernelGGL(qkv_kernel, dim3(NQ / 16, 3), dim3(64), 0, stream,
                     x, wq, bq, wk, bk, wv, bv, th, qq, kvT);
  hipLaunchKernelGGL(flash_kernel, dim3(GRID_FLASH), dim3(FQB), 0, stream,
                     qq, kvT, pO, pL);
  hipLaunchKernelGGL(merge_kernel, dim3(MERGEB), dim3(256), 0, stream,
                     pO, pL, wo, bo, (float*)d_out);
}